// Round 1
// baseline (2618.396 us; speedup 1.0000x reference)
//
#include <hip/hip_runtime.h>
#include <math.h>

#define NND 420
#define MAXE 5120
#define MAXS 65536

// output layout (float element offsets)
#define OFF_X    ((size_t)0)
#define OFF_RI   ((size_t)25600)
#define OFF_RO   ((size_t)25600 + 335544320)
#define OFF_SUY  ((size_t)671114240)
#define OFF_SIDS ((size_t)671179776)
#define OFF_NIDX ((size_t)671310848)
#define OFF_EIDS ((size_t)671315968)
#define OUT_TOTAL ((size_t)671331328)

static __device__ __forceinline__ float f32(double d) { return (float)d; }

__device__ float g_dxn[MAXE], g_dyn[MAXE], g_dzn[MAXE];
__device__ float g_iop[MAXE], g_ioc[MAXE];
__device__ int   g_keep[MAXE], g_istrue[MAXE], g_jn[MAXE];
__device__ int   g_estart[NND + 1];
__device__ int   g_cnt2[MAXE], g_off2[MAXE];
__device__ int   g_nedges, g_nkeep;

// ---------------- Kernel A: nodes -> edges -> per-edge features + small outputs
__global__ __launch_bounds__(512) void kA(const float* __restrict__ ev,
                                          float* __restrict__ out) {
    __shared__ float s_r[NND], s_phi[NND], s_z[NND], s_st[NND], s_trk[NND], s_io[NND];
    __shared__ int   s_cnt[NND];
    __shared__ int   s_off[NND + 1];
    __shared__ short s_ei[MAXE], s_ej[MAXE];

    const float PI_F  = f32(3.141592653589793);
    const float TPI_F = f32(6.283185307179586);
    const float LO1 = -3.15f, SPAN1 = 3.15f + 3.15f;   // exact f32 of C_HI-C_LO
    const float LO2 = -2386.0f, SPAN2 = 4772.0f;
    const float SPAN0 = 312.0f;

    int t = threadIdx.x;
    for (int n = t; n < NND; n += 512) {
        float x = ev[n * 7 + 1], y = ev[n * 7 + 2];
        s_z[n]   = ev[n * 7 + 3];
        s_st[n]  = ev[n * 7 + 4];
        s_trk[n] = ev[n * 7 + 5];
        s_io[n]  = ev[n * 7 + 6];
        s_r[n]   = sqrtf(__fadd_rn(__fmul_rn(x, x), __fmul_rn(y, y)));
        s_phi[n] = atan2f(x, y);   // reference: arctan2(x, y)
    }
    __syncthreads();

    // per-parent-node edge counts (adj: station[j] == station[i]+1), row-major order
    for (int i = t; i < NND; i += 512) {
        float target = s_st[i] + 1.0f;
        int c = 0;
        for (int j = 0; j < NND; ++j) c += (s_st[j] == target) ? 1 : 0;
        s_cnt[i] = c;
    }
    __syncthreads();
    if (t == 0) {
        int acc = 0;
        for (int i = 0; i < NND; ++i) { s_off[i] = acc; acc += s_cnt[i]; }
        s_off[NND] = acc;
        g_nedges = acc;
        for (int n = 0; n <= NND; ++n)
            g_estart[n] = (s_off[n] > MAXE) ? MAXE : s_off[n];
    }
    __syncthreads();

    // build ordered edge list
    for (int i = t; i < NND; i += 512) {
        float target = s_st[i] + 1.0f;
        int k = s_off[i];
        for (int j = 0; j < NND; ++j) {
            if (s_st[j] == target) {
                if (k < MAXE) { s_ei[k] = (short)i; s_ej[k] = (short)j; }
                ++k;
            }
        }
    }
    __syncthreads();

    int nedges = s_off[NND]; if (nedges > MAXE) nedges = MAXE;

    for (int k = t; k < MAXE; k += 512) {
        bool valid = (k < nedges);
        int i = valid ? (int)s_ei[k] : 0;
        int j = valid ? (int)s_ej[k] : 0;
        float phip = s_phi[i], phic = s_phi[j];
        float zp = s_z[i], zc = s_z[j];
        float rp = s_r[i], rc = s_r[j];
        float iop = s_io[i], ioc = s_io[j];
        int istrue = (s_trk[i] == s_trk[j]) ? 1 : 0;

        // _calc_dphi, exact f32 sequence
        float d = __fsub_rn(phic, phip);
        if (d >  PI_F) d = __fsub_rn(d, TPI_F);
        if (d < -PI_F) d = __fadd_rn(d, TPI_F);

        float dzv = __fsub_rn(zc, zp);
        float dxv = __fsub_rn(rc, rp);
        float dxn = __fdiv_rn(__fmul_rn(2.0f, dxv), SPAN0);
        float dyn = __fdiv_rn(__fmul_rn(2.0f, d),   SPAN1);
        float dzn = __fdiv_rn(__fmul_rn(2.0f, dzv), SPAN2);

        bool keep = valid && (dyn > -10.0f) && (dyn < 10.0f)
                          && (dzn > -10.0f) && (dzn < 10.0f);

        // norm_node: 2*(v-lo)/span - 1
        float ypn = __fsub_rn(__fdiv_rn(__fmul_rn(2.0f, __fsub_rn(phip, LO1)), SPAN1), 1.0f);
        float ycn = __fsub_rn(__fdiv_rn(__fmul_rn(2.0f, __fsub_rn(phic, LO1)), SPAN1), 1.0f);
        float zpn = __fsub_rn(__fdiv_rn(__fmul_rn(2.0f, __fsub_rn(zp, LO2)), SPAN2), 1.0f);
        float zcn = __fsub_rn(__fdiv_rn(__fmul_rn(2.0f, __fsub_rn(zc, LO2)), SPAN2), 1.0f);
        float ez  = __fdiv_rn(__fadd_rn(s_st[i], 1.0f), 35.0f);

        if (keep) {  // non-keep rows stay memset-zero
            size_t oX = OFF_X + (size_t)k * 5;
            out[oX + 0] = ypn; out[oX + 1] = ycn; out[oX + 2] = zpn;
            out[oX + 3] = zcn; out[oX + 4] = ez;
        }
        out[OFF_NIDX + (size_t)k] = keep ? (float)k : -1.0f;
        size_t oE = OFF_EIDS + (size_t)k * 3;
        out[oE + 0] = keep ? iop : -1.0f;
        out[oE + 1] = keep ? ioc : -1.0f;
        out[oE + 2] = keep ? (float)k : -1.0f;

        g_dxn[k] = dxn; g_dyn[k] = dyn; g_dzn[k] = dzn;
        g_iop[k] = iop; g_ioc[k] = ioc;
        g_keep[k] = keep ? 1 : 0; g_istrue[k] = istrue; g_jn[k] = j;
    }
}

// ---------------- Kernel B: per-edge-a count of kept super-edges
__global__ __launch_bounds__(256) void kB() {
    int a = blockIdx.x * 256 + threadIdx.x;
    if (a >= MAXE) return;
    int c = 0;
    if (g_keep[a]) {
        int jn = g_jn[a];
        float ioca = g_ioc[a];
        float a0 = g_dxn[a], a1 = g_dyn[a], a2 = g_dzn[a];
        int b0 = g_estart[jn], b1 = g_estart[jn + 1];
        for (int b = b0; b < b1; ++b) {
            if (g_keep[b] && (g_iop[b] == ioca)) {
                float d0 = __fsub_rn(a0, g_dxn[b]);
                float d1 = __fsub_rn(a1, g_dyn[b]);
                float d2 = __fsub_rn(a2, g_dzn[b]);
                float w = sqrtf(__fadd_rn(__fadd_rn(__fmul_rn(d0, d0),
                                                    __fmul_rn(d1, d1)),
                                          __fmul_rn(d2, d2)));
                if (w < 0.1f) ++c;
            }
        }
    }
    g_cnt2[a] = c;
}

// ---------------- Kernel C: exclusive prefix scan over 5120 counts (1 block)
__global__ __launch_bounds__(1024) void kC() {
    __shared__ int part[1024];
    int t = threadIdx.x;
    int v[5]; int s = 0;
#pragma unroll
    for (int q = 0; q < 5; ++q) { v[q] = g_cnt2[t * 5 + q]; s += v[q]; }
    part[t] = s;
    __syncthreads();
    for (int off = 1; off < 1024; off <<= 1) {
        int x = (t >= off) ? part[t - off] : 0;
        __syncthreads();
        part[t] += x;
        __syncthreads();
    }
    int run = part[t] - s;  // exclusive base for this chunk
#pragma unroll
    for (int q = 0; q < 5; ++q) { g_off2[t * 5 + q] = run; run += v[q]; }
    if (t == 1023) g_nkeep = part[1023];
}

// ---------------- Kernel D: emit kept super-edges (order-preserving) + scatter Ri/Ro
__global__ __launch_bounds__(256) void kD(float* __restrict__ out) {
    int a = blockIdx.x * 256 + threadIdx.x;
    if (a >= MAXE) return;
    if (!g_keep[a]) return;
    int pos = g_off2[a];
    int jn = g_jn[a];
    float ioca = g_ioc[a];
    float a0 = g_dxn[a], a1 = g_dyn[a], a2 = g_dzn[a];
    int b0 = g_estart[jn], b1 = g_estart[jn + 1];
    for (int b = b0; b < b1; ++b) {
        if (g_keep[b] && (g_iop[b] == ioca)) {
            float d0 = __fsub_rn(a0, g_dxn[b]);
            float d1 = __fsub_rn(a1, g_dyn[b]);
            float d2 = __fsub_rn(a2, g_dzn[b]);
            float w = sqrtf(__fadd_rn(__fadd_rn(__fmul_rn(d0, d0),
                                                __fmul_rn(d1, d1)),
                                      __fmul_rn(d2, d2)));
            if (w < 0.1f) {
                if (pos < MAXS) {
                    out[OFF_SUY + (size_t)pos] =
                        (g_istrue[a] && g_istrue[b]) ? 1.0f : 0.0f;
                    size_t os = OFF_SIDS + (size_t)pos * 2;
                    out[os + 0] = (float)b;   // su_iop = e_index[se]
                    out[os + 1] = (float)a;   // su_ioc = e_index[fi]
                    out[OFF_RI + (size_t)a * MAXS + (size_t)pos] = 1.0f;
                    out[OFF_RO + (size_t)b * MAXS + (size_t)pos] = 1.0f;
                }
                ++pos;
            }
        }
    }
}

// ---------------- Kernel E: fill invalid super slots with -2
__global__ __launch_bounds__(256) void kE(float* __restrict__ out) {
    int p = blockIdx.x * 256 + threadIdx.x;
    if (p >= MAXS) return;
    if (p >= g_nkeep) {
        size_t os = OFF_SIDS + (size_t)p * 2;
        out[os + 0] = -2.0f;
        out[os + 1] = -2.0f;
    }
}

extern "C" void kernel_launch(void* const* d_in, const int* in_sizes, int n_in,
                              void* d_out, int out_size, void* d_ws, size_t ws_size,
                              hipStream_t stream) {
    const float* ev = (const float*)d_in[0];
    float* out = (float*)d_out;

    // Zero everything: Ri/Ro are ~all-zero one-hot matrices; X/su_y rely on 0 fill.
    hipMemsetAsync(d_out, 0, (size_t)out_size * sizeof(float), stream);

    hipLaunchKernelGGL(kA, dim3(1), dim3(512), 0, stream, ev, out);
    hipLaunchKernelGGL(kB, dim3((MAXE + 255) / 256), dim3(256), 0, stream);
    hipLaunchKernelGGL(kC, dim3(1), dim3(1024), 0, stream);
    hipLaunchKernelGGL(kD, dim3((MAXE + 255) / 256), dim3(256), 0, stream, out);
    hipLaunchKernelGGL(kE, dim3((MAXS + 255) / 256), dim3(256), 0, stream, out);
}